// Round 5
// baseline (6701.826 us; speedup 1.0000x reference)
//
#include <hip/hip_runtime.h>
#include <math.h>

#define Bg 32
#define Ng 2048
#define Kn 20
#define BNn (Bg*Ng)
#define En (BNn*Kn)
#define Hd 64
#define Cd 40
#define CAPB 12
#define CAPG 4

// ---------- weight prep: wpq[d][l<64] = W1a-W1b (x_i side), wpq[d][64+l] = W1b (x_j side)
__global__ void prep_w_kernel(const float* __restrict__ w1c, const float* __restrict__ w1d1,
                              const float* __restrict__ w1d2,
                              float* __restrict__ wpq0, float* __restrict__ wpq1,
                              float* __restrict__ wpq2){
  int t = blockIdx.x*256 + threadIdx.x;
  if (t < 3*128){
    int d = t >> 7, l = t & 127;
    wpq0[t] = (l < 64) ? (w1c[d*64 + l] - w1c[(d+3)*64 + l]) : w1c[(d+3)*64 + (l-64)];
  }
  if (t < 64*128){
    int d = t >> 7, l = t & 127;
    wpq1[t] = (l < 64) ? (w1d1[d*64 + l] - w1d1[(d+64)*64 + l]) : w1d1[(d+64)*64 + (l-64)];
    wpq2[t] = (l < 64) ? (w1d2[d*64 + l] - w1d2[(d+64)*64 + l]) : w1d2[(d+64)*64 + (l-64)];
  }
}

__global__ void zero_kernel(int* __restrict__ p){
  p[blockIdx.x*256 + threadIdx.x] = 0;
}

// ---------- X[BN,D] @ wpq[D,128] -> P[BN,64], Q[BN,64]
template<int D>
__global__ __launch_bounds__(128) void gemm_pq_kernel(const float* __restrict__ x,
                               const float* __restrict__ w,
                               float* __restrict__ P, float* __restrict__ Q){
  __shared__ float xs[8*D];
  int l = threadIdx.x;
  int node0 = blockIdx.x*8;
  float wc[D];
  #pragma unroll
  for (int d=0; d<D; d++) wc[d] = w[d*128 + l];
  for (int i=l; i < 8*D; i += 128) xs[i] = x[(size_t)node0*D + i];
  __syncthreads();
  #pragma unroll
  for (int n=0; n<8; n++){
    float s = 0.f;
    #pragma unroll
    for (int d=0; d<D; d++) s = fmaf(xs[n*D+d], wc[d], s);
    int node = node0 + n;
    if (l < 64) P[(size_t)node*64 + l] = s;
    else        Q[(size_t)node*64 + (l-64)] = s;
  }
}

// ---------- build XT[g][k][j] transpose + row sq norms (lane owns a row; no LDS needed)
__global__ __launch_bounds__(256) void xt_kernel(const float* __restrict__ x,
        float* __restrict__ xt, float* __restrict__ sq){
  int row = blockIdx.x*256 + threadIdx.x;
  const float* xp = x + (size_t)row*Hd;
  float xr[Hd];
  float s = 0.f;
  #pragma unroll
  for (int c=0;c<16;c++){
    float4 v = *(const float4*)(xp + 4*c);
    xr[4*c+0]=v.x; xr[4*c+1]=v.y; xr[4*c+2]=v.z; xr[4*c+3]=v.w;
    s = fmaf(v.x,v.x,s); s = fmaf(v.y,v.y,s);
    s = fmaf(v.z,v.z,s); s = fmaf(v.w,v.w,s);
  }
  sq[row] = s;
  int g = row >> 11, r = row & (Ng-1);
  float* xtg = xt + (size_t)g*Hd*Ng;
  #pragma unroll
  for (int k=0;k<Hd;k++) xtg[(size_t)k*Ng + r] = xr[k];   // coalesced per k
}

// ---------- CSR build for static EdgeConv
__global__ void count_kernel(const int* __restrict__ ei, int* __restrict__ deg){
  int e = blockIdx.x*256 + threadIdx.x;
  atomicAdd(&deg[ei[En + e]], 1);
}

__global__ __launch_bounds__(1024) void scan_kernel(const int* __restrict__ deg,
        int* __restrict__ rowptr, int* __restrict__ cursor){
  __shared__ int ps[1024];
  int t = threadIdx.x;
  int base = t*64;
  int s = 0;
  for (int k=0;k<64;k++) s += deg[base+k];
  ps[t] = s; __syncthreads();
  for (int off=1; off<1024; off<<=1){
    int v = (t>=off) ? ps[t-off] : 0;
    __syncthreads();
    ps[t] += v;
    __syncthreads();
  }
  int run = (t>0) ? ps[t-1] : 0;
  for (int k=0;k<64;k++){
    rowptr[base+k] = run; cursor[base+k] = run;
    run += deg[base+k];
  }
  if (t==1023) rowptr[BNn] = run;
}

__global__ void scatter_kernel(const int* __restrict__ ei, int* __restrict__ cursor,
                               int* __restrict__ csrc){
  int e = blockIdx.x*256 + threadIdx.x;
  int s = ei[e], d = ei[En + e];
  int pos = atomicAdd(&cursor[d], 1);
  csrc[pos] = s;
}

// ---------- static EdgeConv over CSR
__global__ __launch_bounds__(64) void econv_kernel(const int* __restrict__ rowptr,
        const int* __restrict__ csrc,
        const float* __restrict__ P, const float* __restrict__ Q,
        const float* __restrict__ b1, const float* __restrict__ w2,
        const float* __restrict__ b2, float* __restrict__ xout){
  __shared__ __align__(16) float ts[2][Hd];
  int l = threadIdx.x;
  float w2c[Hd];
  #pragma unroll
  for (int d=0; d<Hd; d++) w2c[d] = w2[d*Hd + l];
  float b1l = b1[l], b2l = b2[l];
  for (int i = blockIdx.x; i < BNn; i += gridDim.x){
    int r0 = rowptr[i], r1 = rowptr[i+1];
    float pv = P[(size_t)i*Hd + l] + b1l;
    float acc = -INFINITY;
    for (int k=r0; k<r1; k++){
      int j = csrc[k];
      float tv = pv + Q[(size_t)j*Hd + l];
      tv = tv > 0.f ? tv : 0.f;
      int pb = k & 1;
      ts[pb][l] = tv;
      __syncthreads();
      float s = 0.f;
      #pragma unroll
      for (int d=0; d<Hd; d+=4){
        float4 t4 = *(const float4*)&ts[pb][d];
        s = fmaf(t4.x, w2c[d+0], s);
        s = fmaf(t4.y, w2c[d+1], s);
        s = fmaf(t4.z, w2c[d+2], s);
        s = fmaf(t4.w, w2c[d+3], s);
      }
      acc = fmaxf(acc, s);
    }
    float o = 0.f;
    if (r1 > r0){ o = acc + b2l; o = o > 0.f ? o : expm1f(o); }
    xout[(size_t)i*Hd + l] = o;
  }
}

// ---------- kNN v3: lane owns a row (xr in VGPRs); B wave-uniform via scalar loads of XT
__device__ __forceinline__ void ins20(unsigned long long (&kb)[Kn], unsigned long long key){
  #pragma unroll
  for (int p=Kn-1; p>0; p--){
    unsigned long long ins = (key < kb[p]) ? key : kb[p];
    kb[p] = (key < kb[p-1]) ? kb[p-1] : ins;
  }
  kb[0] = (key < kb[0]) ? key : kb[0];
}

__device__ __forceinline__ void drain_cand(unsigned long long (&kb)[Kn],
    unsigned long long &kb19, int &cnt,
    unsigned long long (*cand)[256], int tid){
  #pragma unroll 1
  for (int c=0; c<CAPB; c++){
    if (!__any(c < cnt)) break;
    unsigned long long k2 = (c < cnt) ? cand[c][tid] : ~0ULL;
    ins20(kb, k2);
  }
  cnt = 0; kb19 = kb[Kn-1];
}

__global__ __launch_bounds__(256,2) void knn_kernel(const float* __restrict__ x,
        const float* __restrict__ xt, const float* __restrict__ sq,
        int* __restrict__ idx){
  __shared__ unsigned long long cand[CAPB][256];     // [slot][tid]: bank-safe (2 lanes/bank)
  __shared__ unsigned long long mbuf[2][64][Kn];     // j-half merge buffer
  int tid = threadIdx.x;
  int lane = tid & 63, wid = tid >> 6;
  int g = blockIdx.x >> 4;                // 16 blocks per graph, 128 rows each
  int pair = wid >> 1, jhalf = wid & 1;   // 2 waves share a row-set, split j-range
  int rloc = (blockIdx.x & 15)*128 + pair*64 + lane;
  int row = g*Ng + rloc;

  float xr[Hd];
  {
    const float* xrp = x + (size_t)row*Hd;
    #pragma unroll
    for (int c=0;c<16;c++){
      float4 v = *(const float4*)(xrp + 4*c);
      xr[4*c+0]=v.x; xr[4*c+1]=v.y; xr[4*c+2]=v.z; xr[4*c+3]=v.w;
    }
  }
  const float* XTg = xt + (size_t)g*Hd*Ng;
  const float* sg  = sq + (size_t)g*Ng;
  int jb = __builtin_amdgcn_readfirstlane(jhalf * (Ng/2));  // force SGPR (wave-uniform)

  unsigned long long kb[Kn];
  #pragma unroll
  for (int t=0;t<Kn;t++) kb[t] = ~0ULL;
  unsigned long long kb19 = ~0ULL;
  int cnt = 0;

  #pragma unroll 1
  for (int jt=0; jt<(Ng/2)/8; jt++){
    int j0 = jb + jt*8;
    const float* bp = XTg + j0;           // wave-uniform -> s_load path
    float acc[8];
    #pragma unroll
    for (int jj=0;jj<8;jj++) acc[jj]=0.f;
    #pragma unroll
    for (int kc=0;kc<16;kc++){
      float bv[4][8];
      #pragma unroll
      for (int kk=0;kk<4;kk++)
        #pragma unroll
        for (int jj=0;jj<8;jj++)
          bv[kk][jj] = bp[(size_t)(kc*4+kk)*Ng + jj];
      #pragma unroll
      for (int kk=0;kk<4;kk++)
        #pragma unroll
        for (int jj=0;jj<8;jj++)
          acc[jj] = fmaf(xr[kc*4+kk], bv[kk][jj], acc[jj]);
    }
    // selection: dist = sq[j] - 2*dot (row-constant +sr dropped; order-invariant)
    #pragma unroll
    for (int jj=0;jj<8;jj++){
      float dist = fmaf(acc[jj], -2.f, sg[j0+jj]);
      unsigned u = __float_as_uint(dist);
      u = ((int)u < 0) ? ~u : (u | 0x80000000u);   // order-preserving fp32->u32
      unsigned long long key = ((unsigned long long)u << 32) | (unsigned)(j0+jj);
      if (key < kb19){ cand[cnt][tid] = key; cnt++; }   // max cnt = 3+8 = 11 < CAPB
    }
    if (__any(cnt >= CAPG)) drain_cand(kb, kb19, cnt, cand, tid);
  }
  drain_cand(kb, kb19, cnt, cand, tid);

  __syncthreads();
  if (jhalf == 1){
    #pragma unroll
    for (int t=0;t<Kn;t++) mbuf[pair][lane][t] = kb[t];
  }
  __syncthreads();
  if (jhalf == 0){
    #pragma unroll 1
    for (int t=0;t<Kn;t++) ins20(kb, mbuf[pair][lane][t]);
    #pragma unroll
    for (int t=0;t<Kn;t++)
      idx[(size_t)row*Kn + t] = g*Ng + (int)(kb[t] & (unsigned long long)(Ng-1));
  }
}

// ---------- dynamic EdgeConv stage 2
template<bool ELU>
__global__ __launch_bounds__(64) void dedge_kernel(const float* __restrict__ P, const float* __restrict__ Q,
        const int* __restrict__ idx, const float* __restrict__ b1,
        const float* __restrict__ w2, const float* __restrict__ b2,
        float* __restrict__ out){
  __shared__ __align__(16) float ts[2][Hd];
  int l = threadIdx.x;
  float w2c[Hd];
  #pragma unroll
  for (int d=0; d<Hd; d++) w2c[d] = w2[d*Hd + l];
  float b1l = b1[l], b2l = b2[l];
  for (int i = blockIdx.x; i < BNn; i += gridDim.x){
    float pv = P[(size_t)i*Hd + l] + b1l;
    float acc = -INFINITY;
    for (int k=0; k<Kn; k++){
      int j = idx[(size_t)i*Kn + k];
      float t = pv + Q[(size_t)j*Hd + l];
      t = t > 0.f ? t : 0.f;
      int pb = k & 1;
      ts[pb][l] = t;
      __syncthreads();
      float s = 0.f;
      #pragma unroll
      for (int d=0; d<Hd; d+=4){
        float4 tv = *(const float4*)&ts[pb][d];
        s = fmaf(tv.x, w2c[d+0], s);
        s = fmaf(tv.y, w2c[d+1], s);
        s = fmaf(tv.z, w2c[d+2], s);
        s = fmaf(tv.w, w2c[d+3], s);
      }
      acc = fmaxf(acc, s);
    }
    float o = acc + b2l;
    if (ELU) o = o > 0.f ? o : expm1f(o);
    out[(size_t)i*Hd + l] = o;
  }
}

__global__ __launch_bounds__(64) void final_kernel(const float* __restrict__ h,
        const float* __restrict__ w, const float* __restrict__ bias,
        float* __restrict__ out){
  __shared__ float xs[Hd];
  int c = threadIdx.x;
  float wc[Hd];
  float bc = 0.f;
  if (c < Cd){
    #pragma unroll
    for (int d=0; d<Hd; d++) wc[d] = w[d*Cd + c];
    bc = bias[c];
  }
  for (int i = blockIdx.x; i < BNn; i += gridDim.x){
    __syncthreads();
    xs[c] = h[(size_t)i*Hd + c];
    __syncthreads();
    if (c < Cd){
      float s = bc;
      #pragma unroll
      for (int d=0; d<Hd; d++) s = fmaf(xs[d], wc[d], s);
      out[(size_t)i*Cd + c] = s;
    }
  }
}

extern "C" void kernel_launch(void* const* d_in, const int* in_sizes, int n_in,
                              void* d_out, int out_size, void* d_ws, size_t ws_size,
                              hipStream_t stream){
  const float* x0   = (const float*)d_in[0];
  const int*   ei   = (const int*)d_in[1];
  const float* c1w1 = (const float*)d_in[3];
  const float* c1b1 = (const float*)d_in[4];
  const float* c1w2 = (const float*)d_in[5];
  const float* c1b2 = (const float*)d_in[6];
  const float* d1w1 = (const float*)d_in[7];
  const float* d1b1 = (const float*)d_in[8];
  const float* d1w2 = (const float*)d_in[9];
  const float* d1b2 = (const float*)d_in[10];
  const float* d2w1 = (const float*)d_in[11];
  const float* d2b1 = (const float*)d_in[12];
  const float* d2w2 = (const float*)d_in[13];
  const float* d2b2 = (const float*)d_in[14];
  const float* linw = (const float*)d_in[15];
  const float* linb = (const float*)d_in[16];
  float* out = (float*)d_out;

  char* ws = (char*)d_ws;
  size_t off = 0;
  auto alloc = [&](size_t bytes)->char*{
    char* p = ws + off; off += (bytes + 255) & ~(size_t)255; return p;
  };
  float* X    = (float*)alloc(sizeof(float)*(size_t)BNn*Hd);
  float* P    = (float*)alloc(sizeof(float)*(size_t)BNn*Hd);
  float* Q    = (float*)alloc(sizeof(float)*(size_t)BNn*Hd);
  float* H2   = (float*)alloc(sizeof(float)*(size_t)BNn*Hd);  // also XT (aliased; disjoint lifetimes)
  int*   SHRD = (int*)alloc(sizeof(int)*(size_t)En);          // CSRC, later IDX
  int*   DEG  = (int*)alloc(sizeof(int)*BNn);
  int*   RPTR = (int*)alloc(sizeof(int)*(BNn+1));
  int*   CUR  = (int*)alloc(sizeof(int)*BNn);
  float* SQ   = (float*)alloc(sizeof(float)*BNn);
  float* WPQ0 = (float*)alloc(sizeof(float)*3*128);
  float* WPQ1 = (float*)alloc(sizeof(float)*64*128);
  float* WPQ2 = (float*)alloc(sizeof(float)*64*128);
  int*   CSRC = SHRD;
  int*   IDX  = SHRD;
  float* XT   = H2;   // alive only between xt_kernel and knn_kernel of each layer
  (void)ws_size; (void)in_sizes; (void)n_in; (void)out_size;

  prep_w_kernel<<<32, 256, 0, stream>>>(c1w1, d1w1, d2w1, WPQ0, WPQ1, WPQ2);
  zero_kernel<<<BNn/256, 256, 0, stream>>>(DEG);
  count_kernel<<<En/256, 256, 0, stream>>>(ei, DEG);
  gemm_pq_kernel<3><<<BNn/8, 128, 0, stream>>>(x0, WPQ0, P, Q);
  scan_kernel<<<1, 1024, 0, stream>>>(DEG, RPTR, CUR);
  scatter_kernel<<<En/256, 256, 0, stream>>>(ei, CUR, CSRC);
  econv_kernel<<<8192, 64, 0, stream>>>(RPTR, CSRC, P, Q, c1b1, c1w2, c1b2, X);

  // dynamic layer 1
  xt_kernel<<<BNn/256, 256, 0, stream>>>(X, XT, SQ);
  gemm_pq_kernel<64><<<BNn/8, 128, 0, stream>>>(X, WPQ1, P, Q);
  knn_kernel<<<Bg*16, 256, 0, stream>>>(X, XT, SQ, IDX);
  dedge_kernel<true><<<8192, 64, 0, stream>>>(P, Q, IDX, d1b1, d1w2, d1b2, X);

  // dynamic layer 2
  xt_kernel<<<BNn/256, 256, 0, stream>>>(X, XT, SQ);
  gemm_pq_kernel<64><<<BNn/8, 128, 0, stream>>>(X, WPQ2, P, Q);
  knn_kernel<<<Bg*16, 256, 0, stream>>>(X, XT, SQ, IDX);
  dedge_kernel<false><<<8192, 64, 0, stream>>>(P, Q, IDX, d2b1, d2w2, d2b2, H2);

  final_kernel<<<8192, 64, 0, stream>>>(H2, linw, linb, out);
}

// Round 6
// 2036.680 us; speedup vs baseline: 3.2906x; 3.2906x over previous
//
#include <hip/hip_runtime.h>
#include <math.h>

#define Bg 32
#define Ng 2048
#define Kn 20
#define BNn (Bg*Ng)
#define En (BNn*Kn)
#define Hd 64
#define Cd 40

// knn tiling (round-4 validated)
#define RT 128
#define JT 32
#define XRS 132
#define XJS 36
#define DSs 33
#define CAPk 4

// ---------- weight prep
__global__ void prep_w_kernel(const float* __restrict__ w1c, const float* __restrict__ w1d1,
                              const float* __restrict__ w1d2,
                              float* __restrict__ wpq0, float* __restrict__ wpq1,
                              float* __restrict__ wpq2){
  int t = blockIdx.x*256 + threadIdx.x;
  if (t < 3*128){
    int d = t >> 7, l = t & 127;
    wpq0[t] = (l < 64) ? (w1c[d*64 + l] - w1c[(d+3)*64 + l]) : w1c[(d+3)*64 + (l-64)];
  }
  if (t < 64*128){
    int d = t >> 7, l = t & 127;
    wpq1[t] = (l < 64) ? (w1d1[d*64 + l] - w1d1[(d+64)*64 + l]) : w1d1[(d+64)*64 + (l-64)];
    wpq2[t] = (l < 64) ? (w1d2[d*64 + l] - w1d2[(d+64)*64 + l]) : w1d2[(d+64)*64 + (l-64)];
  }
}

__global__ void zero_kernel(int* __restrict__ p){
  p[blockIdx.x*256 + threadIdx.x] = 0;
}

__global__ void init_enc_kernel(unsigned int* __restrict__ enc){
  enc[blockIdx.x*256 + threadIdx.x] = 0x007FFFFFu;   // enc(-inf)
}

// ---------- X[BN,D] @ wpq[D,128] -> P,Q
template<int D>
__global__ __launch_bounds__(128) void gemm_pq_kernel(const float* __restrict__ x,
                               const float* __restrict__ w,
                               float* __restrict__ P, float* __restrict__ Q){
  __shared__ float xs[8*D];
  int l = threadIdx.x;
  int node0 = blockIdx.x*8;
  float wc[D];
  #pragma unroll
  for (int d=0; d<D; d++) wc[d] = w[d*128 + l];
  for (int i=l; i < 8*D; i += 128) xs[i] = x[(size_t)node0*D + i];
  __syncthreads();
  #pragma unroll
  for (int n=0; n<8; n++){
    float s = 0.f;
    #pragma unroll
    for (int d=0; d<D; d++) s = fmaf(xs[n*D+d], wc[d], s);
    int node = node0 + n;
    if (l < 64) P[(size_t)node*64 + l] = s;
    else        Q[(size_t)node*64 + (l-64)] = s;
  }
}

__global__ __launch_bounds__(256) void sq_kernel(const float* __restrict__ x, float* __restrict__ sq){
  int t = blockIdx.x*256 + threadIdx.x;
  int node = t >> 6, l = t & 63;
  float v = x[(size_t)node*64 + l];
  float s = v*v;
  #pragma unroll
  for (int o=32; o; o>>=1) s += __shfl_xor(s, o, 64);
  if (l == 0) sq[node] = s;
}

// ---------- CSR build
__global__ void count_kernel(const int* __restrict__ ei, int* __restrict__ deg){
  int e = blockIdx.x*256 + threadIdx.x;
  atomicAdd(&deg[ei[En + e]], 1);
}

__global__ __launch_bounds__(1024) void scan_kernel(const int* __restrict__ deg,
        int* __restrict__ rowptr, int* __restrict__ cursor){
  __shared__ int ps[1024];
  int t = threadIdx.x;
  int base = t*64;
  int s = 0;
  for (int k=0;k<64;k++) s += deg[base+k];
  ps[t] = s; __syncthreads();
  for (int off=1; off<1024; off<<=1){
    int v = (t>=off) ? ps[t-off] : 0;
    __syncthreads();
    ps[t] += v;
    __syncthreads();
  }
  int run = (t>0) ? ps[t-1] : 0;
  for (int k=0;k<64;k++){
    rowptr[base+k] = run; cursor[base+k] = run;
    run += deg[base+k];
  }
  if (t==1023) rowptr[BNn] = run;
}

__global__ void scatter_kernel(const int* __restrict__ ei, int* __restrict__ cursor,
                               int* __restrict__ csrc){
  int e = blockIdx.x*256 + threadIdx.x;
  int s = ei[e], d = ei[En + e];
  int pos = atomicAdd(&cursor[d], 1);
  csrc[pos] = s;
}

// ---------- static EdgeConv over CSR (unchanged)
__global__ __launch_bounds__(64) void econv_kernel(const int* __restrict__ rowptr,
        const int* __restrict__ csrc,
        const float* __restrict__ P, const float* __restrict__ Q,
        const float* __restrict__ b1, const float* __restrict__ w2,
        const float* __restrict__ b2, float* __restrict__ xout){
  __shared__ __align__(16) float ts[2][Hd];
  int l = threadIdx.x;
  float w2c[Hd];
  #pragma unroll
  for (int d=0; d<Hd; d++) w2c[d] = w2[d*Hd + l];
  float b1l = b1[l], b2l = b2[l];
  for (int i = blockIdx.x; i < BNn; i += gridDim.x){
    int r0 = rowptr[i], r1 = rowptr[i+1];
    float pv = P[(size_t)i*Hd + l] + b1l;
    float acc = -INFINITY;
    for (int k=r0; k<r1; k++){
      int j = csrc[k];
      float tv = pv + Q[(size_t)j*Hd + l];
      tv = tv > 0.f ? tv : 0.f;
      int pb = k & 1;
      ts[pb][l] = tv;
      __syncthreads();
      float s = 0.f;
      #pragma unroll
      for (int d=0; d<Hd; d+=4){
        float4 t4 = *(const float4*)&ts[pb][d];
        s = fmaf(t4.x, w2c[d+0], s);
        s = fmaf(t4.y, w2c[d+1], s);
        s = fmaf(t4.z, w2c[d+2], s);
        s = fmaf(t4.w, w2c[d+3], s);
      }
      acc = fmaxf(acc, s);
    }
    float o = 0.f;
    if (r1 > r0){ o = acc + b2l; o = o > 0.f ? o : expm1f(o); }
    xout[(size_t)i*Hd + l] = o;
  }
}

// ---------- kNN (round-4 validated: fused distance-GEMM tile + selection scan)
__device__ __forceinline__ void ins20(unsigned long long (&kb)[Kn], unsigned long long key){
  #pragma unroll
  for (int p=Kn-1; p>0; p--){
    unsigned long long ins = (key < kb[p]) ? key : kb[p];
    kb[p] = (key < kb[p-1]) ? kb[p-1] : ins;
  }
  kb[0] = (key < kb[0]) ? key : kb[0];
}

__global__ __launch_bounds__(256,2) void knn_kernel(const float* __restrict__ x,
        const float* __restrict__ sq, int* __restrict__ idx){
  __shared__ __align__(16) float xr[64*XRS];
  __shared__ __align__(16) float xj[2][64*XJS];
  __shared__ float Dt[RT*DSs];
  __shared__ float sqs[2][JT];
  __shared__ __align__(16) unsigned long long kcand[CAPk][256];

  int tid = threadIdx.x;
  int g = blockIdx.x >> 4;
  int r0 = (blockIdx.x & 15) * RT;
  const float* xg = x + (size_t)g*Ng*Hd;
  const float* sg = sq + (size_t)g*Ng;

  #pragma unroll
  for (int rep = 0; rep < 8; rep++){
    int li = rep*1024 + tid*4;
    int r = li >> 6, k = li & 63;
    float4 v = *(const float4*)(xg + (size_t)(r0+r)*Hd + k);
    xr[(k+0)*XRS + r] = v.x; xr[(k+1)*XRS + r] = v.y;
    xr[(k+2)*XRS + r] = v.z; xr[(k+3)*XRS + r] = v.w;
  }
  {
    int jl = tid & 31, kh = tid >> 5;
    const float* p = xg + (size_t)jl*Hd + kh*8;
    float4 a = *(const float4*)p, b = *(const float4*)(p+4);
    int kk = kh*8;
    xj[0][(kk+0)*XJS+jl]=a.x; xj[0][(kk+1)*XJS+jl]=a.y;
    xj[0][(kk+2)*XJS+jl]=a.z; xj[0][(kk+3)*XJS+jl]=a.w;
    xj[0][(kk+4)*XJS+jl]=b.x; xj[0][(kk+5)*XJS+jl]=b.y;
    xj[0][(kk+6)*XJS+jl]=b.z; xj[0][(kk+7)*XJS+jl]=b.w;
    if (tid < JT) sqs[0][tid] = sg[tid];
  }
  int tr = tid >> 3;
  int tj = tid & 7;
  int lane = tid & 63, w = tid >> 6;
  int rowl = w*32 + (lane & 31);
  int jq = lane >> 5;

  unsigned long long kb[Kn];
  #pragma unroll
  for (int t=0;t<Kn;t++) kb[t] = ~0ULL;
  unsigned long long kb19 = ~0ULL;
  int cnt = 0;

  __syncthreads();

  for (int t = 0; t < Ng/JT; t++){
    int buf = t & 1;
    float4 pa, pb; float psq = 0.f;
    int tn = t + 1;
    int jl = tid & 31, kh = tid >> 5;
    if (tn < Ng/JT){
      const float* p = xg + (size_t)(tn*JT + jl)*Hd + kh*8;
      pa = *(const float4*)p; pb = *(const float4*)(p+4);
      if (tid < JT) psq = sg[tn*JT + tid];
    }
    float acc[16];
    #pragma unroll
    for (int i=0;i<16;i++) acc[i] = 0.f;
    #pragma unroll 8
    for (int k=0;k<64;k++){
      float4 a = *(const float4*)&xr[k*XRS + 4*tr];
      float4 b = *(const float4*)&xj[buf][k*XJS + 4*tj];
      acc[ 0] = fmaf(a.x, b.x, acc[ 0]); acc[ 1] = fmaf(a.x, b.y, acc[ 1]);
      acc[ 2] = fmaf(a.x, b.z, acc[ 2]); acc[ 3] = fmaf(a.x, b.w, acc[ 3]);
      acc[ 4] = fmaf(a.y, b.x, acc[ 4]); acc[ 5] = fmaf(a.y, b.y, acc[ 5]);
      acc[ 6] = fmaf(a.y, b.z, acc[ 6]); acc[ 7] = fmaf(a.y, b.w, acc[ 7]);
      acc[ 8] = fmaf(a.z, b.x, acc[ 8]); acc[ 9] = fmaf(a.z, b.y, acc[ 9]);
      acc[10] = fmaf(a.z, b.z, acc[10]); acc[11] = fmaf(a.z, b.w, acc[11]);
      acc[12] = fmaf(a.w, b.x, acc[12]); acc[13] = fmaf(a.w, b.y, acc[13]);
      acc[14] = fmaf(a.w, b.z, acc[14]); acc[15] = fmaf(a.w, b.w, acc[15]);
    }
    __syncthreads();
    #pragma unroll
    for (int jj=0;jj<4;jj++){
      float sqv = sqs[buf][4*tj+jj];
      #pragma unroll
      for (int rr=0;rr<4;rr++)
        Dt[(4*tr+rr)*DSs + 4*tj+jj] = fmaf(acc[rr*4+jj], -2.f, sqv);
    }
    if (tn < Ng/JT){
      int nb = buf^1, kk = kh*8;
      xj[nb][(kk+0)*XJS+jl]=pa.x; xj[nb][(kk+1)*XJS+jl]=pa.y;
      xj[nb][(kk+2)*XJS+jl]=pa.z; xj[nb][(kk+3)*XJS+jl]=pa.w;
      xj[nb][(kk+4)*XJS+jl]=pb.x; xj[nb][(kk+5)*XJS+jl]=pb.y;
      xj[nb][(kk+6)*XJS+jl]=pb.z; xj[nb][(kk+7)*XJS+jl]=pb.w;
      if (tid < JT) sqs[nb][tid] = psq;
    }
    __syncthreads();
    int jbase = t*JT;
    #pragma unroll
    for (int i=0;i<16;i++){
      int jloc = jq*16 + i;
      float s = Dt[rowl*DSs + jloc];
      unsigned u = __float_as_uint(s);
      u = ((int)u < 0) ? ~u : (u | 0x80000000u);
      unsigned long long key = ((unsigned long long)u << 32) | (unsigned)(jbase + jloc);
      if (key < kb19){ kcand[cnt][tid] = key; cnt++; }
      if (__any(cnt >= CAPk)){
        #pragma unroll 1
        for (int c=0;c<CAPk;c++){
          if (!__any(c < cnt)) break;
          unsigned long long kk2 = (c < cnt) ? kcand[c][tid] : ~0ULL;
          ins20(kb, kk2);
        }
        cnt = 0; kb19 = kb[Kn-1];
      }
    }
  }
  #pragma unroll 1
  for (int c=0;c<CAPk;c++){
    if (!__any(c < cnt)) break;
    unsigned long long kk2 = (c < cnt) ? kcand[c][tid] : ~0ULL;
    ins20(kb, kk2);
  }
  __syncthreads();
  unsigned long long* mg = (unsigned long long*)xr;
  if (jq == 1){
    #pragma unroll
    for (int t=0;t<Kn;t++) mg[rowl*Kn + t] = kb[t];
  }
  __syncthreads();
  if (jq == 0){
    #pragma unroll 1
    for (int t=0;t<Kn;t++) ins20(kb, mg[rowl*Kn + t]);
    int node = g*Ng + r0 + rowl;
    #pragma unroll
    for (int t=0;t<Kn;t++)
      idx[(size_t)node*Kn + t] = g*Ng + (int)(kb[t] & (unsigned long long)(Ng-1));
  }
}

// ---------- dynamic EdgeConv stage 2 as edge-batched GEMM + node-max + atomicMax(enc)
#define FMA8(av, r) \
  acc[r][0]=fmaf(av,b0.x,acc[r][0]); acc[r][1]=fmaf(av,b0.y,acc[r][1]); \
  acc[r][2]=fmaf(av,b0.z,acc[r][2]); acc[r][3]=fmaf(av,b0.w,acc[r][3]); \
  acc[r][4]=fmaf(av,b1v.x,acc[r][4]); acc[r][5]=fmaf(av,b1v.y,acc[r][5]); \
  acc[r][6]=fmaf(av,b1v.z,acc[r][6]); acc[r][7]=fmaf(av,b1v.w,acc[r][7]);

__global__ __launch_bounds__(256,3) void emsg_kernel(
    const int* __restrict__ srcl,
    const float* __restrict__ P, const float* __restrict__ Q,
    const float* __restrict__ b1, const float* __restrict__ w2,
    unsigned int* __restrict__ enc){
  __shared__ __align__(16) char smem[49152];
  float* As = (float*)smem;                 // [32][256] 32KB (staged per k-half)
  float* Ws = (float*)(smem + 32768);       // [64][64] 16KB
  float* p0 = (float*)smem;                 // overlay after GEMM: part seg0 [64][33]
  float* p1 = (float*)(smem + 64*33*4);     // part seg1 [64][33]
  int tid = threadIdx.x;
  int e0 = blockIdx.x * 256;
  int e = e0 + tid;
  int i = e / Kn;
  int j = srcl[e];
  const float* Pr = P + (size_t)i*Hd;
  const float* Qr = Q + (size_t)j*Hd;
  // stage Ws: stride-256 scalar copies (conflict-free)
  #pragma unroll
  for (int c=0;c<16;c++) Ws[c*256 + tid] = w2[c*256 + tid];

  int m0 = tid >> 3, n0 = tid & 7;
  float acc[8][8];
  #pragma unroll
  for (int a=0;a<8;a++)
    #pragma unroll
    for (int b=0;b<8;b++) acc[a][b]=0.f;

  #pragma unroll 1
  for (int kh=0; kh<2; kh++){
    __syncthreads();   // Ws ready / previous half done reading As
    #pragma unroll
    for (int c=0;c<8;c++){
      int k = kh*32 + 4*c;
      float4 q4 = *(const float4*)(Qr + k);
      float4 pk = *(const float4*)(Pr + k);
      float4 b4 = *(const float4*)(b1 + k);
      As[(4*c+0)*256 + tid] = fmaxf(pk.x+q4.x+b4.x, 0.f);
      As[(4*c+1)*256 + tid] = fmaxf(pk.y+q4.y+b4.y, 0.f);
      As[(4*c+2)*256 + tid] = fmaxf(pk.z+q4.z+b4.z, 0.f);
      As[(4*c+3)*256 + tid] = fmaxf(pk.w+q4.w+b4.w, 0.f);
    }
    __syncthreads();
    #pragma unroll 4
    for (int kk=0; kk<32; kk++){
      int k = kh*32 + kk;
      float4 a0 = *(const float4*)&As[kk*256 + 8*m0];
      float4 a1 = *(const float4*)&As[kk*256 + 8*m0 + 4];
      float4 b0 = *(const float4*)&Ws[k*64 + 8*n0];
      float4 b1v = *(const float4*)&Ws[k*64 + 8*n0 + 4];
      FMA8(a0.x, 0) FMA8(a0.y, 1) FMA8(a0.z, 2) FMA8(a0.w, 3)
      FMA8(a1.x, 4) FMA8(a1.y, 5) FMA8(a1.z, 6) FMA8(a1.w, 7)
    }
  }
  // thread-local max split at the (single possible) node boundary in its 8 rows
  int ebase = e0 + 8*m0;
  int nd0 = ebase / Kn;
  int split = (nd0+1)*Kn - ebase; if (split > 8) split = 8;
  float s0[8], s1[8];
  #pragma unroll
  for (int b=0;b<8;b++){ s0[b] = -INFINITY; s1[b] = -INFINITY; }
  #pragma unroll
  for (int a=0;a<8;a++)
    #pragma unroll
    for (int b=0;b<8;b++){
      if (a < split) s0[b] = fmaxf(s0[b], acc[a][b]);
      else           s1[b] = fmaxf(s1[b], acc[a][b]);
    }
  __syncthreads();   // done reading As/Ws; overlay part
  #pragma unroll
  for (int b=0;b<8;b++){
    p0[(8*n0+b)*33 + m0] = s0[b];
    p1[(8*n0+b)*33 + m0] = s1[b];
  }
  __syncthreads();
  // reduce per (node, ch), one atomic per pair
  int nfirst = e0 / Kn;
  int ncnt = (e0 + 255) / Kn - nfirst + 1;
  int ch = tid & 63;
  for (int ln = tid >> 6; ln < ncnt; ln += 4){
    int nd = nfirst + ln;
    int glo = nd*Kn;      if (glo < e0)     glo = e0;
    int ghi = nd*Kn + Kn; if (ghi > e0+256) ghi = e0+256;
    int mlo = (glo - e0) >> 3, mhi = (ghi - 1 - e0) >> 3;
    float v = -INFINITY;
    for (int mm = mlo; mm <= mhi; mm++){
      int bn = (e0 + 8*mm) / Kn;
      if (bn == nd)     v = fmaxf(v, p0[ch*33 + mm]);
      if (bn + 1 == nd) v = fmaxf(v, p1[ch*33 + mm]);
    }
    unsigned u = __float_as_uint(v);
    u = ((int)u < 0) ? ~u : (u | 0x80000000u);
    atomicMax(&enc[(size_t)nd*Hd + ch], u);
  }
}

// ---------- decode: enc -> float, +b2, optional ELU
template<bool ELU>
__global__ __launch_bounds__(256) void decode_kernel(const unsigned int* __restrict__ enc,
         const float* __restrict__ b2, float* __restrict__ x){
  int t = blockIdx.x*256 + threadIdx.x;
  unsigned int e = enc[t];
  unsigned int bits = (e & 0x80000000u) ? (e ^ 0x80000000u) : ~e;
  float f = __uint_as_float(bits);
  if (isfinite(f)) f += b2[t & 63]; else f = 0.f;
  if (ELU) f = f > 0.f ? f : expm1f(f);
  x[t] = f;
}

__global__ __launch_bounds__(64) void final_kernel(const float* __restrict__ h,
        const float* __restrict__ w, const float* __restrict__ bias,
        float* __restrict__ out){
  __shared__ float xs[Hd];
  int c = threadIdx.x;
  float wc[Hd];
  float bc = 0.f;
  if (c < Cd){
    #pragma unroll
    for (int d=0; d<Hd; d++) wc[d] = w[d*Cd + c];
    bc = bias[c];
  }
  for (int i = blockIdx.x; i < BNn; i += gridDim.x){
    __syncthreads();
    xs[c] = h[(size_t)i*Hd + c];
    __syncthreads();
    if (c < Cd){
      float s = bc;
      #pragma unroll
      for (int d=0; d<Hd; d++) s = fmaf(xs[d], wc[d], s);
      out[(size_t)i*Cd + c] = s;
    }
  }
}

extern "C" void kernel_launch(void* const* d_in, const int* in_sizes, int n_in,
                              void* d_out, int out_size, void* d_ws, size_t ws_size,
                              hipStream_t stream){
  const float* x0   = (const float*)d_in[0];
  const int*   ei   = (const int*)d_in[1];
  const float* c1w1 = (const float*)d_in[3];
  const float* c1b1 = (const float*)d_in[4];
  const float* c1w2 = (const float*)d_in[5];
  const float* c1b2 = (const float*)d_in[6];
  const float* d1w1 = (const float*)d_in[7];
  const float* d1b1 = (const float*)d_in[8];
  const float* d1w2 = (const float*)d_in[9];
  const float* d1b2 = (const float*)d_in[10];
  const float* d2w1 = (const float*)d_in[11];
  const float* d2b1 = (const float*)d_in[12];
  const float* d2w2 = (const float*)d_in[13];
  const float* d2b2 = (const float*)d_in[14];
  const float* linw = (const float*)d_in[15];
  const float* linb = (const float*)d_in[16];
  float* out = (float*)d_out;

  char* ws = (char*)d_ws;
  size_t off = 0;
  auto alloc = [&](size_t bytes)->char*{
    char* p = ws + off; off += (bytes + 255) & ~(size_t)255; return p;
  };
  float*        X    = (float*)alloc(sizeof(float)*(size_t)BNn*Hd);
  float*        P    = (float*)alloc(sizeof(float)*(size_t)BNn*Hd);
  float*        Q    = (float*)alloc(sizeof(float)*(size_t)BNn*Hd);
  float*        H2   = (float*)alloc(sizeof(float)*(size_t)BNn*Hd);
  unsigned int* ENC  = (unsigned int*)alloc(sizeof(unsigned)*(size_t)BNn*Hd);
  int*          SHRD = (int*)alloc(sizeof(int)*(size_t)En);   // CSRC, later IDX
  int*          DEG  = (int*)alloc(sizeof(int)*BNn);
  int*          RPTR = (int*)alloc(sizeof(int)*(BNn+1));
  int*          CUR  = (int*)alloc(sizeof(int)*BNn);
  float*        SQ   = (float*)alloc(sizeof(float)*BNn);
  float*        WPQ0 = (float*)alloc(sizeof(float)*3*128);
  float*        WPQ1 = (float*)alloc(sizeof(float)*64*128);
  float*        WPQ2 = (float*)alloc(sizeof(float)*64*128);
  int*          CSRC = SHRD;
  int*          IDX  = SHRD;
  (void)ws_size; (void)in_sizes; (void)n_in; (void)out_size;

  // static EdgeConv (CSR path, unchanged)
  prep_w_kernel<<<32, 256, 0, stream>>>(c1w1, d1w1, d2w1, WPQ0, WPQ1, WPQ2);
  zero_kernel<<<BNn/256, 256, 0, stream>>>(DEG);
  count_kernel<<<En/256, 256, 0, stream>>>(ei, DEG);
  gemm_pq_kernel<3><<<BNn/8, 128, 0, stream>>>(x0, WPQ0, P, Q);
  scan_kernel<<<1, 1024, 0, stream>>>(DEG, RPTR, CUR);
  scatter_kernel<<<En/256, 256, 0, stream>>>(ei, CUR, CSRC);
  econv_kernel<<<8192, 64, 0, stream>>>(RPTR, CSRC, P, Q, c1b1, c1w2, c1b2, X);

  // dynamic layer 1
  sq_kernel<<<BNn*Hd/256, 256, 0, stream>>>(X, SQ);
  gemm_pq_kernel<64><<<BNn/8, 128, 0, stream>>>(X, WPQ1, P, Q);
  knn_kernel<<<Bg*(Ng/RT), 256, 0, stream>>>(X, SQ, IDX);
  init_enc_kernel<<<BNn*Hd/256, 256, 0, stream>>>(ENC);
  emsg_kernel<<<En/256, 256, 0, stream>>>(IDX, P, Q, d1b1, d1w2, ENC);
  decode_kernel<true><<<BNn*Hd/256, 256, 0, stream>>>(ENC, d1b2, X);

  // dynamic layer 2
  sq_kernel<<<BNn*Hd/256, 256, 0, stream>>>(X, SQ);
  gemm_pq_kernel<64><<<BNn/8, 128, 0, stream>>>(X, WPQ2, P, Q);
  knn_kernel<<<Bg*(Ng/RT), 256, 0, stream>>>(X, SQ, IDX);
  init_enc_kernel<<<BNn*Hd/256, 256, 0, stream>>>(ENC);
  emsg_kernel<<<En/256, 256, 0, stream>>>(IDX, P, Q, d2b1, d2w2, ENC);
  decode_kernel<false><<<BNn*Hd/256, 256, 0, stream>>>(ENC, d2b2, H2);

  final_kernel<<<8192, 64, 0, stream>>>(H2, linw, linb, out);
}